// Round 7
// baseline (149.674 us; speedup 1.0000x reference)
//
#include <hip/hip_runtime.h>
#include <math.h>

#define BATCH 16384
#define EDIM 128
#define RD (128 * 128)
#define NREL 200
#define G 16
#define S 8
#define STRIPE (BATCH / S)   // 2048
#define PERT (STRIPE / 256)  // 8
#define NBLKS (NREL * S)     // 1600
#define NTHR 256

// ws layout (32-bit words):
//  [0 .. NBLKS)   csum[] (float, per-block loss sums)
//  [2048]         arrival counter (zeroed each launch via memset node)

__device__ __forceinline__ int load_idx(const void* p, int b, int is64) {
    if (is64) return (int)((const long long*)p)[b];
    return ((const int*)p)[b];
}

__global__ __launch_bounds__(NTHR) void mega_kernel(
    const void* __restrict__ hI, const void* __restrict__ rI,
    const void* __restrict__ pI, const void* __restrict__ nI,
    const float* __restrict__ ent, const float* __restrict__ rel,
    unsigned int* __restrict__ ws, float* __restrict__ out) {
    const int t = threadIdx.x;
    const int bid = blockIdx.x;
    const int rid = bid >> 3;
    const int stripe = bid & 7;

    __shared__ __attribute__((aligned(16))) float hT[EDIM][G];  // [d][g]
    __shared__ __attribute__((aligned(16))) float tp[G][EDIM];
    __shared__ __attribute__((aligned(16))) float tn[G][EDIM];
    __shared__ float e2a[G];
    __shared__ float red[2][4][G];
    __shared__ unsigned int sA[256], sB[256];
    __shared__ unsigned int um4[4];
    __shared__ float sm4r[4];
    __shared__ float s_bsum;
    __shared__ int s_last;
    __shared__ int sidx[G];

    // ---- dtype detect (per block, redundant) ----
    {
        unsigned int o = ((const unsigned int*)hI)[2 * t + 1] |
                         ((const unsigned int*)rI)[2 * t + 1] |
                         ((const unsigned int*)pI)[2 * t + 1] |
                         ((const unsigned int*)nI)[2 * t + 1];
#pragma unroll
        for (int off = 32; off > 0; off >>= 1) o |= __shfl_xor(o, off, 64);
        if ((t & 63) == 0) um4[t >> 6] = o;
        if (t == 0) s_bsum = 0.f;
        __syncthreads();
    }
    const int is64 = ((um4[0] | um4[1] | um4[2] | um4[3]) == 0u) ? 1 : 0;

    // ---- scan own stripe: which elements have r == rid ----
    const int base = stripe * STRIPE + t * PERT;
    int r8[PERT];
    int cnt_local = 0;
#pragma unroll
    for (int j = 0; j < PERT; ++j) {
        r8[j] = load_idx(rI, base + j, is64);
        cnt_local += (r8[j] == rid);
    }
    sA[t] = (unsigned int)cnt_local;
    __syncthreads();
    unsigned int *pa = sA, *pb = sB;
    for (int off = 1; off < 256; off <<= 1) {
        const unsigned int v = pa[t] + ((t >= off) ? pa[t - off] : 0u);
        pb[t] = v;
        __syncthreads();
        unsigned int* tm = pa; pa = pb; pb = tm;
    }
    const int cnt = (int)pa[255];
    const int excl = (int)pa[t] - cnt_local;

    float* csum = (float*)ws;
    unsigned int* counter = ws + 2048;
    const float* R = rel + (size_t)rid * RD;
    const int rowsel = t >> 5;
    const int ebase = (t & 31) * 4;

    for (int g0 = 0; g0 < cnt; g0 += G) {
        const int cg = (cnt - g0 < G) ? (cnt - g0) : G;
        // ---- extraction: deterministic rank -> sidx slot ----
        {
            int rk = excl;
#pragma unroll
            for (int j = 0; j < PERT; ++j) {
                if (r8[j] == rid) {
                    if (rk >= g0 && rk < g0 + G) sidx[rk - g0] = base + j;
                    ++rk;
                }
            }
        }
        __syncthreads();

        // ---- stage: 16 lanes per element g; lane l covers dims l*8..l*8+7 ----
        {
            const int g = t >> 4, l = t & 15;
            float e2 = 0.f;
            if (g < cg) {
                const int b = sidx[g];
                const int hi = load_idx(hI, b, is64);
                const int pi = load_idx(pI, b, is64);
                const int ni = load_idx(nI, b, is64);
                const float4* hr = (const float4*)(ent + (size_t)hi * EDIM) + l * 2;
                const float4* pr = (const float4*)(ent + (size_t)pi * EDIM) + l * 2;
                const float4* nr = (const float4*)(ent + (size_t)ni * EDIM) + l * 2;
#pragma unroll
                for (int j = 0; j < 2; ++j) {
                    const float4 hv = hr[j], pv = pr[j], nv = nr[j];
                    const int d0 = l * 8 + j * 4;
                    hT[d0 + 0][g] = hv.x;
                    hT[d0 + 1][g] = hv.y;
                    hT[d0 + 2][g] = hv.z;
                    hT[d0 + 3][g] = hv.w;
                    *(float4*)&tp[g][d0] = pv;
                    *(float4*)&tn[g][d0] = nv;
                    e2 += hv.x * hv.x + hv.y * hv.y + hv.z * hv.z + hv.w * hv.w;
                    e2 += pv.x * pv.x + pv.y * pv.y + pv.z * pv.z + pv.w * pv.w;
                    e2 += nv.x * nv.x + nv.y * nv.y + nv.z * nv.z + nv.w * nv.w;
                }
            } else {
                const float4 z = make_float4(0.f, 0.f, 0.f, 0.f);
#pragma unroll
                for (int j = 0; j < 2; ++j) {
                    const int d0 = l * 8 + j * 4;
                    hT[d0 + 0][g] = 0.f;
                    hT[d0 + 1][g] = 0.f;
                    hT[d0 + 2][g] = 0.f;
                    hT[d0 + 3][g] = 0.f;
                    *(float4*)&tp[g][d0] = z;
                    *(float4*)&tn[g][d0] = z;
                }
            }
            e2 += __shfl_xor(e2, 1, 64);
            e2 += __shfl_xor(e2, 2, 64);
            e2 += __shfl_xor(e2, 4, 64);
            e2 += __shfl_xor(e2, 8, 64);
            if (l == 0) e2a[g] = e2;
        }
        __syncthreads();

        // ---- stream R once: FMA core + inline r2 ----
        float4 acc[G];
#pragma unroll
        for (int g = 0; g < G; ++g) acc[g] = make_float4(0.f, 0.f, 0.f, 0.f);
        float r2acc = 0.f;
#pragma unroll
        for (int k = 0; k < 16; ++k) {
            const float4 rv = *(const float4*)(R + k * 1024 + t * 4);
            r2acc = fmaf(rv.x, rv.x, r2acc);
            r2acc = fmaf(rv.y, rv.y, r2acc);
            r2acc = fmaf(rv.z, rv.z, r2acc);
            r2acc = fmaf(rv.w, rv.w, r2acc);
            const int dd = 8 * k + rowsel;
            const float4* hp = (const float4*)&hT[dd][0];
#pragma unroll
            for (int q = 0; q < 4; ++q) {
                const float4 h4 = hp[q];
                acc[4 * q + 0].x = fmaf(rv.x, h4.x, acc[4 * q + 0].x);
                acc[4 * q + 0].y = fmaf(rv.y, h4.x, acc[4 * q + 0].y);
                acc[4 * q + 0].z = fmaf(rv.z, h4.x, acc[4 * q + 0].z);
                acc[4 * q + 0].w = fmaf(rv.w, h4.x, acc[4 * q + 0].w);
                acc[4 * q + 1].x = fmaf(rv.x, h4.y, acc[4 * q + 1].x);
                acc[4 * q + 1].y = fmaf(rv.y, h4.y, acc[4 * q + 1].y);
                acc[4 * q + 1].z = fmaf(rv.z, h4.y, acc[4 * q + 1].z);
                acc[4 * q + 1].w = fmaf(rv.w, h4.y, acc[4 * q + 1].w);
                acc[4 * q + 2].x = fmaf(rv.x, h4.z, acc[4 * q + 2].x);
                acc[4 * q + 2].y = fmaf(rv.y, h4.z, acc[4 * q + 2].y);
                acc[4 * q + 2].z = fmaf(rv.z, h4.z, acc[4 * q + 2].z);
                acc[4 * q + 2].w = fmaf(rv.w, h4.z, acc[4 * q + 2].w);
                acc[4 * q + 3].x = fmaf(rv.x, h4.w, acc[4 * q + 3].x);
                acc[4 * q + 3].y = fmaf(rv.y, h4.w, acc[4 * q + 3].y);
                acc[4 * q + 3].z = fmaf(rv.z, h4.w, acc[4 * q + 3].z);
                acc[4 * q + 3].w = fmaf(rv.w, h4.w, acc[4 * q + 3].w);
            }
        }

        const int lane = t & 63, wave = t >> 6;
#pragma unroll
        for (int g = 0; g < G; ++g) {
            const float4 tpv = *(const float4*)&tp[g][ebase];
            const float4 tnv = *(const float4*)&tn[g][ebase];
            float dp = acc[g].x * tpv.x + acc[g].y * tpv.y + acc[g].z * tpv.z + acc[g].w * tpv.w;
            float dn = acc[g].x * tnv.x + acc[g].y * tnv.y + acc[g].z * tnv.z + acc[g].w * tnv.w;
            for (int off = 32; off > 0; off >>= 1) {
                dp += __shfl_down(dp, off, 64);
                dn += __shfl_down(dn, off, 64);
            }
            if (lane == 0) {
                red[0][wave][g] = dp;
                red[1][wave][g] = dn;
            }
        }
        // r2 block-reduce (same value every group; overwrite is fine)
        {
            float rr = r2acc;
            for (int off = 32; off > 0; off >>= 1) rr += __shfl_down(rr, off, 64);
            if (lane == 0) sm4r[wave] = rr;
        }
        __syncthreads();

        float s = 0.f;
        if (t < cg) {
            const float SP = red[0][0][t] + red[0][1][t] + red[0][2][t] + red[0][3][t];
            const float SN = red[1][0][t] + red[1][1][t] + red[1][2][t] + red[1][3][t];
            const float r2v = sm4r[0] + sm4r[1] + sm4r[2] + sm4r[3];
            const float x = SN - SP; // neg_score - pos_score
            const float sploss = (x > 0.f) ? (x + log1pf(expf(-x))) : log1pf(expf(x));
            s = sploss + 1e-5f * 0.5f * (e2a[t] + r2v);
        }
        if (t < 16) {
            s += __shfl_down(s, 8, 16);
            s += __shfl_down(s, 4, 16);
            s += __shfl_down(s, 2, 16);
            s += __shfl_down(s, 1, 16);
            if (t == 0) s_bsum += s;
        }
        __syncthreads(); // protect sidx/hT/red/sm4r/s_bsum for next group
    }

    // ---- publish block sum, arrive, last block reduces ----
    if (t == 0) {
        __hip_atomic_store(&csum[bid], (cnt > 0) ? s_bsum : 0.f,
                           __ATOMIC_RELEASE, __HIP_MEMORY_SCOPE_AGENT);
        __threadfence();
        const unsigned int old = atomicAdd(counter, 1u);
        s_last = (old == (unsigned int)(NBLKS - 1)) ? 1 : 0;
    }
    __syncthreads();
    if (s_last) {
        __threadfence();
        float a = 0.f;
        for (int i = t; i < NBLKS; i += NTHR)
            a += __hip_atomic_load(&csum[i], __ATOMIC_ACQUIRE, __HIP_MEMORY_SCOPE_AGENT);
#pragma unroll
        for (int off = 32; off > 0; off >>= 1) a += __shfl_down(a, off, 64);
        if ((t & 63) == 0) sm4r[t >> 6] = a;
        __syncthreads();
        if (t == 0)
            out[0] = (sm4r[0] + sm4r[1] + sm4r[2] + sm4r[3]) * (1.0f / (float)BATCH);
    }
}

extern "C" void kernel_launch(void* const* d_in, const int* in_sizes, int n_in,
                              void* d_out, int out_size, void* d_ws, size_t ws_size,
                              hipStream_t stream) {
    const void* h = d_in[0];
    const void* r = d_in[1];
    const void* pt = d_in[2];
    const void* nt = d_in[3];
    const float* ent = (const float*)d_in[4];
    const float* rel = (const float*)d_in[5];
    unsigned int* ws = (unsigned int*)d_ws;

    // zero the arrival counter (ws word 2048) every launch — capture-legal memset node
    hipMemsetAsync((void*)((char*)d_ws + 2048 * sizeof(unsigned int)), 0,
                   sizeof(unsigned int), stream);
    mega_kernel<<<NBLKS, NTHR, 0, stream>>>(h, r, pt, nt, ent, rel, ws, (float*)d_out);
}

// Round 8
// 96.187 us; speedup vs baseline: 1.5561x; 1.5561x over previous
//
#include <hip/hip_runtime.h>
#include <math.h>

#define BATCH 16384
#define EDIM 128
#define RD (EDIM * EDIM)   // 16384 floats = 64 KB
#define NREL 200
#define G 16
#define NTHR 512
#define PERT (BATCH / NTHR)  // 32
#define LISTCAP 2048

__device__ __forceinline__ int load_idx(const void* p, int b, int is64) {
    if (is64) return (int)((const long long*)p)[b];
    return ((const int*)p)[b];
}

// One block per relation. Stages the 64KB relation matrix in LDS ONCE,
// self-discovers its batch elements (deterministic scan of r), then
// processes them in groups of 16 with all R reads served from LDS.
__global__ __launch_bounds__(NTHR) void rescal_kernel(
    const void* __restrict__ hI, const void* __restrict__ rI,
    const void* __restrict__ pI, const void* __restrict__ nI,
    const float* __restrict__ ent, const float* __restrict__ rel,
    float* __restrict__ out) {
    const int t = threadIdx.x;
    const int rid = blockIdx.x;
    const int lane = t & 63;
    const int wave = t >> 6;

    __shared__ __attribute__((aligned(16))) float Rl[RD];        // 64 KB
    __shared__ __attribute__((aligned(16))) float hT[EDIM][G];   // 8 KB [d][g]
    __shared__ __attribute__((aligned(16))) float tp[G][EDIM];   // 8 KB
    __shared__ __attribute__((aligned(16))) float tn[G][EDIM];   // 8 KB
    __shared__ unsigned short list[LISTCAP];                     // 4 KB
    __shared__ float red[2][8][G];                               // 1 KB
    __shared__ float e2a[G];
    __shared__ float wred[8];
    __shared__ unsigned int wtot[8];
    __shared__ unsigned int um8[8];
    __shared__ float s_bsum, s_r2;

    // ---- dtype detect (first 256 elements' odd words, all 4 index arrays) ----
    unsigned int o = 0u;
    if (t < 256) {
        o = ((const unsigned int*)hI)[2 * t + 1] | ((const unsigned int*)rI)[2 * t + 1] |
            ((const unsigned int*)pI)[2 * t + 1] | ((const unsigned int*)nI)[2 * t + 1];
    }
#pragma unroll
    for (int off = 32; off; off >>= 1) o |= __shfl_xor(o, off, 64);
    if (lane == 0) um8[wave] = o;
    if (t == 0) s_bsum = 0.f;
    __syncthreads();
    const int is64 = ((um8[0] | um8[1] | um8[2] | um8[3] |
                      um8[4] | um8[5] | um8[6] | um8[7]) == 0u) ? 1 : 0;

    // ---- stage R row to LDS (64 KB, coalesced float4) ----
    const float* Rg = rel + (size_t)rid * RD;
#pragma unroll
    for (int it = 0; it < 8; ++it) {
        const int idx = it * (NTHR * 4) + t * 4;
        *(float4*)&Rl[idx] = *(const float4*)(Rg + idx);
    }

    // ---- pass 1: count my elements ----
    int cl = 0;
    for (int j = 0; j < PERT; ++j) cl += (load_idx(rI, t * PERT + j, is64) == rid);
    // wave-inclusive prefix
    int incl = cl;
#pragma unroll
    for (int off = 1; off < 64; off <<= 1) {
        const int nv = __shfl_up(incl, off, 64);
        if (lane >= off) incl += nv;
    }
    if (lane == 63) wtot[wave] = (unsigned int)incl;
    __syncthreads();  // Rl + wtot complete past here
    int base = 0;
    for (int w = 0; w < wave; ++w) base += (int)wtot[w];
    int cnt = 0;
    for (int w = 0; w < 8; ++w) cnt += (int)wtot[w];
    if (cnt > LISTCAP) cnt = LISTCAP;
    // pass 2: emit list (deterministic rank; r re-reads are L1/L2-hot)
    {
        int rk = base + incl - cl;
        for (int j = 0; j < PERT; ++j) {
            if (load_idx(rI, t * PERT + j, is64) == rid) {
                if (rk < LISTCAP) list[rk] = (unsigned short)(t * PERT + j);
                ++rk;
            }
        }
    }

    // ---- r2 from the LDS copy ----
    const int c4 = (t & 31) * 4;   // my 4 columns
    const int rsel = t >> 5;       // my row-slice 0..15 (rows rsel*8 .. rsel*8+7)
    {
        float r2p = 0.f;
#pragma unroll
        for (int k = 0; k < 8; ++k) {
            const float4 rv = *(const float4*)&Rl[(rsel * 8 + k) * EDIM + c4];
            r2p = fmaf(rv.x, rv.x, fmaf(rv.y, rv.y, fmaf(rv.z, rv.z, fmaf(rv.w, rv.w, r2p))));
        }
#pragma unroll
        for (int off = 32; off; off >>= 1) r2p += __shfl_down(r2p, off, 64);
        if (lane == 0) wred[wave] = r2p;
    }
    __syncthreads();  // list + wred complete
    if (t == 0) {
        float s = 0.f;
        for (int w = 0; w < 8; ++w) s += wred[w];
        s_r2 = s;
    }
    __syncthreads();

    // ---- groups of G elements; R from LDS ----
    for (int g0 = 0; g0 < cnt; g0 += G) {
        const int cg = (cnt - g0 < G) ? (cnt - g0) : G;

        // stage: 32 lanes per element; lane l covers dims l*4..l*4+3
        {
            const int g = t >> 5, l = t & 31;
            if (g < cg) {
                const int b = (int)list[g0 + g];
                const int hi = load_idx(hI, b, is64);
                const int pi = load_idx(pI, b, is64);
                const int ni = load_idx(nI, b, is64);
                const float4 hv = *(const float4*)(ent + (size_t)hi * EDIM + l * 4);
                const float4 pv = *(const float4*)(ent + (size_t)pi * EDIM + l * 4);
                const float4 nv = *(const float4*)(ent + (size_t)ni * EDIM + l * 4);
                hT[l * 4 + 0][g] = hv.x;
                hT[l * 4 + 1][g] = hv.y;
                hT[l * 4 + 2][g] = hv.z;
                hT[l * 4 + 3][g] = hv.w;
                *(float4*)&tp[g][l * 4] = pv;
                *(float4*)&tn[g][l * 4] = nv;
                float e2 = hv.x * hv.x + hv.y * hv.y + hv.z * hv.z + hv.w * hv.w +
                           pv.x * pv.x + pv.y * pv.y + pv.z * pv.z + pv.w * pv.w +
                           nv.x * nv.x + nv.y * nv.y + nv.z * nv.z + nv.w * nv.w;
                e2 += __shfl_xor(e2, 16, 64);
                e2 += __shfl_xor(e2, 8, 64);
                e2 += __shfl_xor(e2, 4, 64);
                e2 += __shfl_xor(e2, 2, 64);
                e2 += __shfl_xor(e2, 1, 64);
                if (l == 0) e2a[g] = e2;
            }
        }
        __syncthreads();

        // k-loop: my 8 rows x my 4 cols, all 16 elements; R and h from LDS
        float4 acc[G];
#pragma unroll
        for (int g = 0; g < G; ++g) acc[g] = make_float4(0.f, 0.f, 0.f, 0.f);
#pragma unroll
        for (int k = 0; k < 8; ++k) {
            const int dd = rsel * 8 + k;
            const float4 rv = *(const float4*)&Rl[dd * EDIM + c4];
            const float4* hp = (const float4*)&hT[dd][0];
            const float4 h0 = hp[0], h1 = hp[1], h2 = hp[2], h3 = hp[3];
            acc[0].x = fmaf(rv.x, h0.x, acc[0].x);
            acc[0].y = fmaf(rv.y, h0.x, acc[0].y);
            acc[0].z = fmaf(rv.z, h0.x, acc[0].z);
            acc[0].w = fmaf(rv.w, h0.x, acc[0].w);
            acc[1].x = fmaf(rv.x, h0.y, acc[1].x);
            acc[1].y = fmaf(rv.y, h0.y, acc[1].y);
            acc[1].z = fmaf(rv.z, h0.y, acc[1].z);
            acc[1].w = fmaf(rv.w, h0.y, acc[1].w);
            acc[2].x = fmaf(rv.x, h0.z, acc[2].x);
            acc[2].y = fmaf(rv.y, h0.z, acc[2].y);
            acc[2].z = fmaf(rv.z, h0.z, acc[2].z);
            acc[2].w = fmaf(rv.w, h0.z, acc[2].w);
            acc[3].x = fmaf(rv.x, h0.w, acc[3].x);
            acc[3].y = fmaf(rv.y, h0.w, acc[3].y);
            acc[3].z = fmaf(rv.z, h0.w, acc[3].z);
            acc[3].w = fmaf(rv.w, h0.w, acc[3].w);
            acc[4].x = fmaf(rv.x, h1.x, acc[4].x);
            acc[4].y = fmaf(rv.y, h1.x, acc[4].y);
            acc[4].z = fmaf(rv.z, h1.x, acc[4].z);
            acc[4].w = fmaf(rv.w, h1.x, acc[4].w);
            acc[5].x = fmaf(rv.x, h1.y, acc[5].x);
            acc[5].y = fmaf(rv.y, h1.y, acc[5].y);
            acc[5].z = fmaf(rv.z, h1.y, acc[5].z);
            acc[5].w = fmaf(rv.w, h1.y, acc[5].w);
            acc[6].x = fmaf(rv.x, h1.z, acc[6].x);
            acc[6].y = fmaf(rv.y, h1.z, acc[6].y);
            acc[6].z = fmaf(rv.z, h1.z, acc[6].z);
            acc[6].w = fmaf(rv.w, h1.z, acc[6].w);
            acc[7].x = fmaf(rv.x, h1.w, acc[7].x);
            acc[7].y = fmaf(rv.y, h1.w, acc[7].y);
            acc[7].z = fmaf(rv.z, h1.w, acc[7].z);
            acc[7].w = fmaf(rv.w, h1.w, acc[7].w);
            acc[8].x = fmaf(rv.x, h2.x, acc[8].x);
            acc[8].y = fmaf(rv.y, h2.x, acc[8].y);
            acc[8].z = fmaf(rv.z, h2.x, acc[8].z);
            acc[8].w = fmaf(rv.w, h2.x, acc[8].w);
            acc[9].x = fmaf(rv.x, h2.y, acc[9].x);
            acc[9].y = fmaf(rv.y, h2.y, acc[9].y);
            acc[9].z = fmaf(rv.z, h2.y, acc[9].z);
            acc[9].w = fmaf(rv.w, h2.y, acc[9].w);
            acc[10].x = fmaf(rv.x, h2.z, acc[10].x);
            acc[10].y = fmaf(rv.y, h2.z, acc[10].y);
            acc[10].z = fmaf(rv.z, h2.z, acc[10].z);
            acc[10].w = fmaf(rv.w, h2.z, acc[10].w);
            acc[11].x = fmaf(rv.x, h2.w, acc[11].x);
            acc[11].y = fmaf(rv.y, h2.w, acc[11].y);
            acc[11].z = fmaf(rv.z, h2.w, acc[11].z);
            acc[11].w = fmaf(rv.w, h2.w, acc[11].w);
            acc[12].x = fmaf(rv.x, h3.x, acc[12].x);
            acc[12].y = fmaf(rv.y, h3.x, acc[12].y);
            acc[12].z = fmaf(rv.z, h3.x, acc[12].z);
            acc[12].w = fmaf(rv.w, h3.x, acc[12].w);
            acc[13].x = fmaf(rv.x, h3.y, acc[13].x);
            acc[13].y = fmaf(rv.y, h3.y, acc[13].y);
            acc[13].z = fmaf(rv.z, h3.y, acc[13].z);
            acc[13].w = fmaf(rv.w, h3.y, acc[13].w);
            acc[14].x = fmaf(rv.x, h3.z, acc[14].x);
            acc[14].y = fmaf(rv.y, h3.z, acc[14].y);
            acc[14].z = fmaf(rv.z, h3.z, acc[14].z);
            acc[14].w = fmaf(rv.w, h3.z, acc[14].w);
            acc[15].x = fmaf(rv.x, h3.w, acc[15].x);
            acc[15].y = fmaf(rv.y, h3.w, acc[15].y);
            acc[15].z = fmaf(rv.z, h3.w, acc[15].z);
            acc[15].w = fmaf(rv.w, h3.w, acc[15].w);
        }

        // tails + reduce over 64 lanes, publish per-wave partials
#pragma unroll
        for (int g = 0; g < G; ++g) {
            const float4 tpv = *(const float4*)&tp[g][c4];
            const float4 tnv = *(const float4*)&tn[g][c4];
            float dp = acc[g].x * tpv.x + acc[g].y * tpv.y + acc[g].z * tpv.z + acc[g].w * tpv.w;
            float dn = acc[g].x * tnv.x + acc[g].y * tnv.y + acc[g].z * tnv.z + acc[g].w * tnv.w;
#pragma unroll
            for (int off = 32; off; off >>= 1) {
                dp += __shfl_down(dp, off, 64);
                dn += __shfl_down(dn, off, 64);
            }
            if (lane == 0) {
                red[0][wave][g] = dp;
                red[1][wave][g] = dn;
            }
        }
        __syncthreads();

        float s = 0.f;
        if (t < cg) {
            float SP = 0.f, SN = 0.f;
#pragma unroll
            for (int w = 0; w < 8; ++w) {
                SP += red[0][w][t];
                SN += red[1][w][t];
            }
            const float x = SN - SP;  // = neg_score - pos_score
            const float spl = (x > 0.f) ? (x + log1pf(expf(-x))) : log1pf(expf(x));
            s = spl + 1e-5f * 0.5f * (e2a[t] + s_r2);
        }
        if (t < 16) {
            s += __shfl_down(s, 8, 16);
            s += __shfl_down(s, 4, 16);
            s += __shfl_down(s, 2, 16);
            s += __shfl_down(s, 1, 16);
            if (t == 0) s_bsum += s;
        }
        __syncthreads();  // protect hT/tp/tn/red/e2a/s_bsum for next group
    }

    if (t == 0 && cnt > 0) atomicAdd(out, s_bsum * (1.0f / (float)BATCH));
}

extern "C" void kernel_launch(void* const* d_in, const int* in_sizes, int n_in,
                              void* d_out, int out_size, void* d_ws, size_t ws_size,
                              hipStream_t stream) {
    const void* h = d_in[0];
    const void* r = d_in[1];
    const void* pt = d_in[2];
    const void* nt = d_in[3];
    const float* ent = (const float*)d_in[4];
    const float* rel = (const float*)d_in[5];

    hipMemsetAsync(d_out, 0, sizeof(float), stream);  // capture-legal
    rescal_kernel<<<NREL, NTHR, 0, stream>>>(h, r, pt, nt, ent, rel, (float*)d_out);
}

// Round 9
// 63.177 us; speedup vs baseline: 2.3691x; 1.5225x over previous
//
#include <hip/hip_runtime.h>
#include <math.h>

#define BATCH 16384
#define EDIM 128
#define RD (EDIM * EDIM)     // 16384 floats = 64 KB
#define NREL 200
#define SPLIT 2
#define NBLK (NREL * SPLIT)  // 400
#define NTHR 512
#define HALF (BATCH / SPLIT) // 8192
#define PERT (HALF / NTHR)   // 16
#define G 16
#define LISTCAP 512

__device__ __forceinline__ int load_idx(const void* p, int b, int is64) {
    if (is64) return (int)((const long long*)p)[b];
    return ((const int*)p)[b];
}

// Block (rid, half): stages the 64KB relation matrix in LDS once, finds its
// elements in its batch-half, processes groups of 16 (one element per
// 32-lane replica; acc = one float4/thread).
__global__ __launch_bounds__(NTHR, 4) void rescal_kernel(
    const void* __restrict__ hI, const void* __restrict__ rI,
    const void* __restrict__ pI, const void* __restrict__ nI,
    const float* __restrict__ ent, const float* __restrict__ rel,
    float* __restrict__ out) {
    const int t = threadIdx.x;
    const int rid = blockIdx.x >> 1;
    const int half = blockIdx.x & 1;
    const int lane = t & 63;
    const int wave = t >> 6;
    const int rep = t >> 5;   // 0..15
    const int l32 = t & 31;
    const int c4 = l32 * 4;   // my 4 columns

    __shared__ __attribute__((aligned(16))) float Rl[RD];          // 64 KB
    __shared__ float hT[EDIM][G + 1];                              // 8.7 KB, padded
    __shared__ unsigned short list[LISTCAP];
    __shared__ float red[3][G];
    __shared__ float h2a[G];
    __shared__ unsigned int wtot[8], um8[8];
    __shared__ float wred[8];
    __shared__ float s_bsum, s_r2;

    // ---- dtype detect ----
    unsigned int o = 0u;
    if (t < 256) {
        o = ((const unsigned int*)hI)[2 * t + 1] | ((const unsigned int*)rI)[2 * t + 1] |
            ((const unsigned int*)pI)[2 * t + 1] | ((const unsigned int*)nI)[2 * t + 1];
    }
#pragma unroll
    for (int off = 32; off; off >>= 1) o |= __shfl_xor(o, off, 64);
    if (lane == 0) um8[wave] = o;
    if (t == 0) s_bsum = 0.f;
    __syncthreads();
    const int is64 = ((um8[0] | um8[1] | um8[2] | um8[3] |
                       um8[4] | um8[5] | um8[6] | um8[7]) == 0u) ? 1 : 0;

    // ---- stage R to LDS (coalesced float4) ----
    const float* Rg = rel + (size_t)rid * RD;
#pragma unroll
    for (int it = 0; it < 8; ++it) {
        const int idx = it * (NTHR * 4) + t * 4;
        *(float4*)&Rl[idx] = *(const float4*)(Rg + idx);
    }

    // ---- find my elements in my batch-half (deterministic) ----
    const int base0 = half * HALF + t * PERT;
    int cl = 0;
#pragma unroll
    for (int j = 0; j < PERT; ++j) cl += (load_idx(rI, base0 + j, is64) == rid);
    int incl = cl;
#pragma unroll
    for (int off = 1; off < 64; off <<= 1) {
        const int nv = __shfl_up(incl, off, 64);
        if (lane >= off) incl += nv;
    }
    if (lane == 63) wtot[wave] = (unsigned int)incl;
    __syncthreads();  // Rl + wtot ready
    int base = 0, cnt = 0;
#pragma unroll
    for (int w = 0; w < 8; ++w) {
        const int wv = (int)wtot[w];
        base += (w < wave) ? wv : 0;
        cnt += wv;
    }
    if (cnt > LISTCAP) cnt = LISTCAP;
    {
        int rk = base + incl - cl;
        for (int j = 0; j < PERT; ++j) {
            if (load_idx(rI, base0 + j, is64) == rid) {
                if (rk < LISTCAP) list[rk] = (unsigned short)(base0 + j);
                ++rk;
            }
        }
    }

    // ---- r2 from LDS copy ----
    {
        float r2p = 0.f;
#pragma unroll
        for (int j = 0; j < 8; ++j) {
            const float4 v = *(const float4*)&Rl[t * 32 + j * 4];
            r2p = fmaf(v.x, v.x, fmaf(v.y, v.y, fmaf(v.z, v.z, fmaf(v.w, v.w, r2p))));
        }
#pragma unroll
        for (int off = 32; off; off >>= 1) r2p += __shfl_down(r2p, off, 64);
        if (lane == 0) wred[wave] = r2p;
    }
    __syncthreads();  // list + wred ready
    if (t == 0) {
        float s = 0.f;
        for (int w = 0; w < 8; ++w) s += wred[w];
        s_r2 = s;
    }
    __syncthreads();

    // ---- groups of G=16: replica rep owns element list[g0+rep] ----
    for (int g0 = 0; g0 < cnt; g0 += G) {
        const int cg = (cnt - g0 < G) ? (cnt - g0) : G;

        // stage h row (transposed) + |h|^2
        if (rep < cg) {
            const int b = (int)list[g0 + rep];
            const int hi = load_idx(hI, b, is64);
            const float4 hv = *(const float4*)(ent + (size_t)hi * EDIM + c4);
            hT[c4 + 0][rep] = hv.x;
            hT[c4 + 1][rep] = hv.y;
            hT[c4 + 2][rep] = hv.z;
            hT[c4 + 3][rep] = hv.w;
            float h2 = hv.x * hv.x + hv.y * hv.y + hv.z * hv.z + hv.w * hv.w;
            h2 += __shfl_xor(h2, 16, 64);
            h2 += __shfl_xor(h2, 8, 64);
            h2 += __shfl_xor(h2, 4, 64);
            h2 += __shfl_xor(h2, 2, 64);
            h2 += __shfl_xor(h2, 1, 64);
            if (l32 == 0) h2a[rep] = h2;
        }
        __syncthreads();

        if (rep < cg) {
            // u[c] = sum_d h[d] * R[d][c] over my 4 columns
            float4 acc = make_float4(0.f, 0.f, 0.f, 0.f);
#pragma unroll 8
            for (int d = 0; d < EDIM; ++d) {
                const float4 rv = *(const float4*)&Rl[d * EDIM + c4];
                const float hd = hT[d][rep];
                acc.x = fmaf(rv.x, hd, acc.x);
                acc.y = fmaf(rv.y, hd, acc.y);
                acc.z = fmaf(rv.z, hd, acc.z);
                acc.w = fmaf(rv.w, hd, acc.w);
            }
            // tails from global (coalesced 512B per replica)
            const int b = (int)list[g0 + rep];
            const int pi = load_idx(pI, b, is64);
            const int ni = load_idx(nI, b, is64);
            const float4 tpv = *(const float4*)(ent + (size_t)pi * EDIM + c4);
            const float4 tnv = *(const float4*)(ent + (size_t)ni * EDIM + c4);
            float dp = acc.x * tpv.x + acc.y * tpv.y + acc.z * tpv.z + acc.w * tpv.w;
            float dn = acc.x * tnv.x + acc.y * tnv.y + acc.z * tnv.z + acc.w * tnv.w;
            float e2 = tpv.x * tpv.x + tpv.y * tpv.y + tpv.z * tpv.z + tpv.w * tpv.w +
                       tnv.x * tnv.x + tnv.y * tnv.y + tnv.z * tnv.z + tnv.w * tnv.w;
#pragma unroll
            for (int off = 16; off; off >>= 1) {
                dp += __shfl_xor(dp, off, 64);
                dn += __shfl_xor(dn, off, 64);
                e2 += __shfl_xor(e2, off, 64);
            }
            if (l32 == 0) {
                red[0][rep] = dp;
                red[1][rep] = dn;
                red[2][rep] = h2a[rep] + e2;
            }
        }
        __syncthreads();

        float s = 0.f;
        if (t < cg) {
            const float SP = red[0][t];
            const float SN = red[1][t];
            const float x = SN - SP;  // neg_score - pos_score
            const float spl = (x > 0.f) ? (x + log1pf(expf(-x))) : log1pf(expf(x));
            s = spl + 1e-5f * 0.5f * (red[2][t] + s_r2);
        }
        if (t < 64) {
#pragma unroll
            for (int off = 32; off; off >>= 1) s += __shfl_down(s, off, 64);
            if (t == 0) s_bsum += s;
        }
        __syncthreads();  // red/hT free for next group
    }

    if (t == 0 && cnt > 0) atomicAdd(out, s_bsum * (1.0f / (float)BATCH));
}

extern "C" void kernel_launch(void* const* d_in, const int* in_sizes, int n_in,
                              void* d_out, int out_size, void* d_ws, size_t ws_size,
                              hipStream_t stream) {
    const void* h = d_in[0];
    const void* r = d_in[1];
    const void* pt = d_in[2];
    const void* nt = d_in[3];
    const float* ent = (const float*)d_in[4];
    const float* rel = (const float*)d_in[5];

    hipMemsetAsync(d_out, 0, sizeof(float), stream);  // capture-legal
    rescal_kernel<<<NBLK, NTHR, 0, stream>>>(h, r, pt, nt, ent, rel, (float*)d_out);
}